// Round 1
// baseline (121.617 us; speedup 1.0000x reference)
//
#include <hip/hip_runtime.h>

// Problem dims (fixed): B=4, T=2048, C=64, H=6, D=64, scale = 1/8.
// I/O dtype: float32 (bf16-rounded values). Internal Q/K/Vt/att are bf16.
// Round-13: attn staging rebuilt as T3/T4 "minimum 2-phase" pipeline:
//  - global_load_lds (16B) direct HBM->LDS, NO register round trip (the
//    r10/r11 spill pathology is structurally impossible).
//  - double-buffered 32KB slabs (64KB LDS, 2 blocks/CU): slab t+1 loads
//    issued before compute of slab t; counted s_waitcnt vmcnt(8) keeps
//    them in flight across the raw s_barrier (never drained in-loop).
//  - LDS layouts are linear (gload_lds requirement); bank conflicts fixed
//    by XOR-swizzling chunk ^= (row&7) on BOTH the global source address
//    and the read address (rule #21: same involution both sides).
// Compute math (S^T MFMA, exp2 softmax, packed BK=128 PV, masks, epilogue)
// is byte-identical to r12. prep/qkv/proj unchanged.

typedef unsigned short u16t;
typedef __attribute__((ext_vector_type(8))) short short8;   // 8 bf16 (MFMA A/B frag)
typedef __attribute__((ext_vector_type(4))) float float4v;  // MFMA C/D frag

#define MFMA16(a, b, c) __builtin_amdgcn_mfma_f32_16x16x32_bf16((a), (b), (c), 0, 0, 0)

union U8 { short8 s; unsigned u[4]; };

__device__ __forceinline__ float fexp2(float x) {  // v_exp_f32: D = 2^S0
  return __builtin_amdgcn_exp2f(x);
}
__device__ __forceinline__ float bf2f(u16t u) {
  return __uint_as_float(((unsigned)u) << 16);
}
__device__ __forceinline__ u16t f2bf(float f) {  // round-nearest-even
  unsigned u = __float_as_uint(f);
  u += 0x7fffu + ((u >> 16) & 1u);
  return (u16t)(u >> 16);
}
__device__ __forceinline__ unsigned bftr(float f) {  // truncated bf16 bits (P only)
  return __float_as_uint(f) >> 16;
}
__device__ __forceinline__ short8 load8_f32_bf16(const float* p) {
  float4 f0 = *(const float4*)p;
  float4 f1 = *(const float4*)(p + 4);
  short8 r;
  r[0] = (short)f2bf(f0.x); r[1] = (short)f2bf(f0.y);
  r[2] = (short)f2bf(f0.z); r[3] = (short)f2bf(f0.w);
  r[4] = (short)f2bf(f1.x); r[5] = (short)f2bf(f1.y);
  r[6] = (short)f2bf(f1.z); r[7] = (short)f2bf(f1.w);
  return r;
}
// async 16B global -> LDS (dest = wave-uniform base + lane*16)
__device__ __forceinline__ void ld16(const void* g, void* l) {
  __builtin_amdgcn_global_load_lds(
      (const __attribute__((address_space(1))) unsigned int*)g,
      (__attribute__((address_space(3))) unsigned int*)l, 16, 0, 0);
}

constexpr int Bb = 4, Tt = 2048, Cc = 64, Hh = 6, Dd = 64;
constexpr int BH = Bb * Hh;         // 24
constexpr int NQT = Tt / 64;        // 32 q-tiles of 64 rows
constexpr int LDT = 72;             // 64-col LDS row stride (qkv kernel)
constexpr int OST = 65;             // f32 O-reduction stride
// exp2-domain: S' = S*log2(e), folded into the Q epilogue scale.
#define QSCALE (0.125f * 1.44269504088896f)

// ---------------------------------------------------------------------------
// Kernel 0: weight prep — convert + transpose all weights to bf16 ONCE.
// ---------------------------------------------------------------------------
__global__ __launch_bounds__(256) void prep_kernel(
    const float* __restrict__ Wq, const float* __restrict__ Wk,
    const float* __restrict__ Wv, const float* __restrict__ Wp,
    u16t* __restrict__ Wqt, u16t* __restrict__ Wkt,
    u16t* __restrict__ Wvt, u16t* __restrict__ Wpt) {
  int idx = blockIdx.x * 256 + threadIdx.x;  // 0..24575
  {  // head matrices: out[h][d][c] <- in[h][c][d]
    int h = idx >> 12, dc = idx & 4095, d = dc >> 6, c = dc & 63;
    int src = h * 4096 + c * 64 + d;
    Wqt[idx] = f2bf(Wq[src]);
    Wkt[idx] = f2bf(Wk[src]);
    Wvt[idx] = f2bf(Wv[src]);
  }
  {  // Wp: out[c][r] <- in[r][c], c in [0,64), r in [0,384)
    int c = idx / 384, r = idx - c * 384;
    Wpt[idx] = f2bf(Wp[r * 64 + c]);
  }
}

// ---------------------------------------------------------------------------
// Kernel 1: QKV projection via MFMA; pure uint4 weight staging (prepped bf16).
// ---------------------------------------------------------------------------
__global__ __launch_bounds__(256) void qkv_kernel(
    const float* __restrict__ x, const float* __restrict__ y,
    const u16t* __restrict__ Wqt, const u16t* __restrict__ Wkt,
    const u16t* __restrict__ Wvt,
    u16t* __restrict__ Q, u16t* __restrict__ K, u16t* __restrict__ Vt) {
  __shared__ __align__(16) u16t wtq[64 * LDT];
  __shared__ __align__(16) u16t wtk[64 * LDT];
  __shared__ __align__(16) u16t wtv[64 * LDT];

  int bid = blockIdx.x;
  int bh = bid >> 5, tt = bid & 31;
  int b = bh / Hh, h = bh - b * Hh;
  int tid = threadIdx.x;
  int w = tid >> 6, lane = tid & 63;
  int l15 = lane & 15, q4 = lane >> 4;

  {  // stage prepped weights: 512 chunks of 8 bf16 per matrix, 2/thread
    const u16t* wq = Wqt + h * 4096;
    const u16t* wk = Wkt + h * 4096;
    const u16t* wv = Wvt + h * 4096;
#pragma unroll
    for (int i = 0; i < 2; ++i) {
      int id = tid * 2 + i;  // 0..511
      int row = id >> 3, c8 = id & 7;
      *(uint4*)&wtq[row * LDT + c8 * 8] = *(const uint4*)(wq + id * 8);
      *(uint4*)&wtk[row * LDT + c8 * 8] = *(const uint4*)(wk + id * 8);
      *(uint4*)&wtv[row * LDT + c8 * 8] = *(const uint4*)(wv + id * 8);
    }
  }

  int trow = tt * 64 + w * 16 + l15;
  const float* xrow = x + ((size_t)b * Tt + trow) * Cc;
  const float* yrow = y + ((size_t)b * Tt + trow) * Cc;
  short8 xa[2], ya[2];
#pragma unroll
  for (int kc = 0; kc < 2; ++kc) {
    xa[kc] = load8_f32_bf16(xrow + kc * 32 + q4 * 8);
    ya[kc] = load8_f32_bf16(yrow + kc * 32 + q4 * 8);
  }
  __syncthreads();  // barrier 1: weights staged

  float4v qa4[4], ka4[4], va4[4];
#pragma unroll
  for (int nc = 0; nc < 4; ++nc) {
    qa4[nc] = (float4v){0.f, 0.f, 0.f, 0.f};
    ka4[nc] = (float4v){0.f, 0.f, 0.f, 0.f};
    va4[nc] = (float4v){0.f, 0.f, 0.f, 0.f};
  }
#pragma unroll
  for (int nc = 0; nc < 4; ++nc) {
#pragma unroll
    for (int kc = 0; kc < 2; ++kc) {
      int off = (nc * 16 + l15) * LDT + kc * 32 + q4 * 8;
      short8 bq = *(const short8*)&wtq[off];
      short8 bk = *(const short8*)&wtk[off];
      short8 bv = *(const short8*)&wtv[off];
      qa4[nc] = MFMA16(xa[kc], bq, qa4[nc]);
      ka4[nc] = MFMA16(ya[kc], bk, ka4[nc]);
      va4[nc] = MFMA16(ya[kc], bv, va4[nc]);
    }
  }
  __syncthreads();  // barrier 2: weights read; reuse LDS as store bounce

#pragma unroll
  for (int reg = 0; reg < 4; ++reg) {
    int rloc = w * 16 + q4 * 4 + reg;
#pragma unroll
    for (int nc = 0; nc < 4; ++nc) {
      wtq[rloc * LDT + nc * 16 + l15] = f2bf(qa4[nc][reg] * QSCALE);
      wtk[rloc * LDT + nc * 16 + l15] = f2bf(ka4[nc][reg]);
      wtv[(nc * 16 + l15) * LDT + rloc] = f2bf(va4[nc][reg]);  // transposed V
    }
  }
  __syncthreads();  // barrier 3

  size_t tilebase = ((size_t)bh * Tt + tt * 64) * Dd;
#pragma unroll
  for (int i = 0; i < 2; ++i) {
    int id = tid * 2 + i;
    int row = id >> 3, c8 = id & 7;
    *(uint4*)&Q[tilebase + row * 64 + c8 * 8] = *(const uint4*)&wtq[row * LDT + c8 * 8];
    *(uint4*)&K[tilebase + row * 64 + c8 * 8] = *(const uint4*)&wtk[row * LDT + c8 * 8];
    *(uint4*)&Vt[((size_t)bh * 64 + row) * Tt + tt * 64 + c8 * 8] =
        *(const uint4*)&wtv[row * LDT + c8 * 8];
  }
}

// ---------------------------------------------------------------------------
// Kernel 2: transpose-free causal flash attention, packed BK=128, pipelined.
// LDS: two 32KB buffers, each {K slab [128][64] bf16 linear-swizzled (16KB),
// V slab [64][128] bf16 linear-swizzled (16KB)}. Swizzle: 16B chunk index
// c ^= (row & 7) — applied to the pre-swizzled global SOURCE address of
// global_load_lds AND to every read address (same involution both sides).
// Per slab: issue next-slab gload_lds -> s_waitcnt vmcnt(8) -> s_barrier ->
// compute -> s_barrier. vmcnt never drains to 0 inside the loop.
// Grid: 768 (qt descending), 256 thr, LDS 64 KB (2 blocks/CU).
// ---------------------------------------------------------------------------
__global__ __launch_bounds__(256) void attn_kernel(
    const u16t* __restrict__ Q, const u16t* __restrict__ K,
    const u16t* __restrict__ Vt, u16t* __restrict__ att) {
  __shared__ __align__(1024) unsigned char smem[2 * 32768];  // 64 KB
  float* Ol = (float*)smem;                    // [64][OST] f32 (epilogue overlay)
  float* Ll = (float*)(smem + 64 * OST * 4);   // [64] f32

  int bid = blockIdx.x;
  int bh = bid % BH;
  int qt = (NQT - 1) - bid / BH;  // big tiles first
  int b = bh / Hh, h = bh - (bh / Hh) * Hh;
  int tid = threadIdx.x;
  int w = tid >> 6;
  int lane = tid & 63;
  int l15 = lane & 15, q4 = lane >> 4;

  const u16t* Kbh = K + (size_t)bh * Tt * Dd;
  const u16t* Vbh = Vt + (size_t)bh * Dd * Tt;
  const int bsmax = qt >> 1;

  // Pre-swizzled per-lane staging SOURCE offsets (bytes within a slab).
  // Dest chunk P (= seg*64 + lane, 16B units) receives logical chunk
  // (row, cph ^ (row&7)) so that LDS physical (row, cph) holds it.
  int koff[4], voff[4];
#pragma unroll
  for (int s = 0; s < 4; ++s) {
    int P = (w * 4 + s) * 64 + lane;          // 0..1023
    int kr = P >> 3;                          // K: 128 rows x 8 chunks
    koff[s] = kr * 128 + (((P & 7) ^ (kr & 7)) << 4);
    int vr = P >> 4;                          // V: 64 rows x 16 chunks
    voff[s] = vr * (Tt * 2) + (((P & 15) ^ (vr & 7)) << 4);
  }

  // Prologue: stage slab 0 into buffer 0 (issue only; waited at barrier A).
  {
    const unsigned char* ks = (const unsigned char*)Kbh;
    const unsigned char* vs = (const unsigned char*)Vbh;
#pragma unroll
    for (int s = 0; s < 4; ++s) {
      ld16(ks + koff[s], smem + ((w * 4 + s) << 10));
      ld16(vs + voff[s], smem + 16384 + ((w * 4 + s) << 10));
    }
  }

  // Q B-frags for all 4 i-tiles (held in regs for the whole kernel).
  short8 qf[4][2];
#pragma unroll
  for (int it = 0; it < 4; ++it) {
    const u16t* qb = Q + ((size_t)bh * Tt + qt * 64 + it * 16 + l15) * Dd;
    qf[it][0] = *(const short8*)(qb + q4 * 8);
    qf[it][1] = *(const short8*)(qb + 32 + q4 * 8);
  }

  // Loop-invariant swizzled READ addresses (bytes).
  int krow = w * 16 + l15;
  int ka0 = krow * 128 + ((q4 ^ (krow & 7)) << 4);   // kf00; kf01 = ^64
  int va_[4];                                        // vf lo; hi = ^128
#pragma unroll
  for (int nc = 0; nc < 4; ++nc) {
    int vr = nc * 16 + l15;
    va_[nc] = vr * 256 + (q4 & 1) * 8 + (((w * 2 + (q4 >> 1)) ^ (vr & 7)) << 4);
  }

  float4v O[4][4];  // [itile][nc] partial O over this wave's j slices
#pragma unroll
  for (int it = 0; it < 4; ++it)
#pragma unroll
    for (int nc = 0; nc < 4; ++nc) O[it][nc] = (float4v){0.f, 0.f, 0.f, 0.f};
  float l_[4] = {0.f, 0.f, 0.f, 0.f};  // per-itile partial row sums (row = l15)

  for (int bs = 0; bs <= bsmax; ++bs) {
    int cur = bs & 1;
    unsigned char* Kb = smem + cur * 32768;
    unsigned char* Vb = Kb + 16384;

    if (bs < bsmax) {  // issue next-slab loads into the other buffer
      unsigned char* Kn = smem + (cur ^ 1) * 32768;
      const unsigned char* ks = (const unsigned char*)(Kbh + (size_t)(bs + 1) * 128 * 64);
      const unsigned char* vs = (const unsigned char*)(Vbh + (bs + 1) * 128);
#pragma unroll
      for (int s = 0; s < 4; ++s) {
        ld16(ks + koff[s], Kn + ((w * 4 + s) << 10));
        ld16(vs + voff[s], Kn + 16384 + ((w * 4 + s) << 10));
      }
      asm volatile("s_waitcnt vmcnt(8)");  // slab bs complete; bs+1 in flight
    } else {
      asm volatile("s_waitcnt vmcnt(0)");  // last slab: drain
    }
    __builtin_amdgcn_s_barrier();          // barrier A: LDS ready (no drain)
    __builtin_amdgcn_sched_barrier(0);     // rule #18: pin ds_reads below

    bool d0 = (2 * bs == qt);      // half0 is the diagonal tile
    bool s1 = (2 * bs + 1 > qt);   // half1 beyond the diagonal (skip)
    bool d1 = (2 * bs + 1 == qt);  // half1 is the diagonal tile

    // This wave's K A-frags for both halves, and packed V B-frags.
    short8 kf00 = *(const short8*)(Kb + ka0);
    short8 kf01 = *(const short8*)(Kb + (ka0 ^ 64));
    short8 kf10 = kf00, kf11 = kf01;
    if (!s1) {
      kf10 = *(const short8*)(Kb + 8192 + ka0);
      kf11 = *(const short8*)(Kb + 8192 + (ka0 ^ 64));
    }
    short8 vf[4];
#pragma unroll
    for (int nc = 0; nc < 4; ++nc) {
      U8 t;
      *(uint2*)&t.u[0] = *(const uint2*)(Vb + va_[nc]);
      *(uint2*)&t.u[2] = *(const uint2*)(Vb + (va_[nc] ^ 128));
      vf[nc] = t.s;
    }

#pragma unroll
    for (int it = 0; it < 4; ++it) {
      if (d0 && w > it) continue;  // half0 fully masked (implies s1): nothing
      float4v S0 = (float4v){0.f, 0.f, 0.f, 0.f};
      S0 = MFMA16(kf00, qf[it][0], S0);
      S0 = MFMA16(kf01, qf[it][1], S0);
      bool m0 = d0 && (w == it);
      float p0[4], p1[4];
#pragma unroll
      for (int reg = 0; reg < 4; ++reg) {
        p0[reg] = (m0 && (q4 * 4 + reg) > l15) ? 0.f : fexp2(S0[reg]);
        l_[it] += p0[reg];
      }
      if (s1 || (d1 && w > it)) {
#pragma unroll
        for (int reg = 0; reg < 4; ++reg) p1[reg] = 0.f;
      } else {
        float4v S1 = (float4v){0.f, 0.f, 0.f, 0.f};
        S1 = MFMA16(kf10, qf[it][0], S1);
        S1 = MFMA16(kf11, qf[it][1], S1);
        bool m1 = d1 && (w == it);
#pragma unroll
        for (int reg = 0; reg < 4; ++reg) {
          p1[reg] = (m1 && (q4 * 4 + reg) > l15) ? 0.f : fexp2(S1[reg]);
          l_[it] += p1[reg];
        }
      }
      U8 pa;  // half0 -> k-slots 0..3, half1 -> 4..7 (matches vf packing)
      pa.u[0] = bftr(p0[0]) | (bftr(p0[1]) << 16);
      pa.u[1] = bftr(p0[2]) | (bftr(p0[3]) << 16);
      pa.u[2] = bftr(p1[0]) | (bftr(p1[1]) << 16);
      pa.u[3] = bftr(p1[2]) | (bftr(p1[3]) << 16);
#pragma unroll
      for (int nc = 0; nc < 4; ++nc)
        O[it][nc] = MFMA16(pa.s, vf[nc], O[it][nc]);
    }

    __builtin_amdgcn_sched_barrier(0);
    __builtin_amdgcn_s_barrier();  // barrier B: reads done; next stage may write
    __builtin_amdgcn_sched_barrier(0);
  }

  // Reduce l_ over q4 groups; lanes then hold wave-total per (itile, i=l15).
#pragma unroll
  for (int it = 0; it < 4; ++it) {
    l_[it] += __shfl_xor(l_[it], 16);
    l_[it] += __shfl_xor(l_[it], 32);
  }

  // Band-rotated cross-wave reduction with compile-time register indices.
  __syncthreads();  // full drain before LDS overlay reuse
#pragma unroll
  for (int r = 0; r < 4; ++r) {
#pragma unroll
    for (int itc = 0; itc < 4; ++itc) {
      if (((itc - w) & 3) == r) {  // wave-uniform branch, itc compile-time
#pragma unroll
        for (int nc = 0; nc < 4; ++nc)
#pragma unroll
          for (int reg = 0; reg < 4; ++reg) {
            int addr = (itc * 16 + q4 * 4 + reg) * OST + nc * 16 + l15;
            if (r == 0) Ol[addr] = O[itc][nc][reg];
            else        Ol[addr] += O[itc][nc][reg];
          }
        if (q4 == 0) {
          if (r == 0) Ll[itc * 16 + l15] = l_[itc];
          else        Ll[itc * 16 + l15] += l_[itc];
        }
      }
    }
    __syncthreads();
  }

  // Normalize + store att[b, t, h*64+d] (coalesced uint4).
#pragma unroll
  for (int i = 0; i < 2; ++i) {
    int id = tid * 2 + i;
    int row = id >> 3, c8 = id & 7;
    float inv = 1.0f / Ll[row];
    const float* orow = &Ol[row * OST + c8 * 8];
    U8 o;
#pragma unroll
    for (int k = 0; k < 4; ++k)
      o.u[k] = f2bf(orow[2 * k] * inv) | ((unsigned)f2bf(orow[2 * k + 1] * inv) << 16);
    int t = qt * 64 + row;
    *(uint4*)&att[((size_t)b * Tt + t) * (Hh * Dd) + h * Dd + c8 * 8] = *(const uint4*)&o;
  }
}

// ---------------------------------------------------------------------------
// Kernel 3: out = att[8192, 384] @ W_proj[384, 64] + b_proj (prepped Wpt).
// ---------------------------------------------------------------------------
constexpr int LDP = 392;  // 384+8

__global__ __launch_bounds__(256) void proj_kernel(
    const u16t* __restrict__ att, const u16t* __restrict__ Wpt,
    const float* __restrict__ bp, float* __restrict__ out) {
  __shared__ __align__(16) u16t wpt[64 * LDP];  // 50176 B

  int bid = blockIdx.x;
  int tid = threadIdx.x;
  int w = tid >> 6, lane = tid & 63;
  int l15 = lane & 15, q4 = lane >> 4;

#pragma unroll
  for (int i = 0; i < 12; ++i) {
    int id = tid + i * 256;  // 0..3071 chunks of 8 bf16
    int r = id / 48, c8 = id - r * 48;
    *(uint4*)&wpt[r * LDP + c8 * 8] = *(const uint4*)(Wpt + id * 8);
  }
  __syncthreads();

  int row0 = bid * 64 + w * 16;
  const u16t* arow = att + (size_t)(row0 + l15) * 384;

  float4v acc[4];
#pragma unroll
  for (int nc = 0; nc < 4; ++nc) acc[nc] = (float4v){0.f, 0.f, 0.f, 0.f};

#pragma unroll
  for (int kc = 0; kc < 12; ++kc) {
    short8 a = *(const short8*)(arow + kc * 32 + q4 * 8);
#pragma unroll
    for (int nc = 0; nc < 4; ++nc) {
      short8 bfr = *(const short8*)&wpt[(nc * 16 + l15) * LDP + kc * 32 + q4 * 8];
      acc[nc] = MFMA16(a, bfr, acc[nc]);
    }
  }

  float bv[4];
#pragma unroll
  for (int nc = 0; nc < 4; ++nc) bv[nc] = bp[nc * 16 + l15];
#pragma unroll
  for (int reg = 0; reg < 4; ++reg) {
    int t = row0 + q4 * 4 + reg;
    size_t obase = (size_t)t * 64;
#pragma unroll
    for (int nc = 0; nc < 4; ++nc)
      out[obase + nc * 16 + l15] = acc[nc][reg] + bv[nc];
  }
}

// ---------------------------------------------------------------------------
extern "C" void kernel_launch(void* const* d_in, const int* in_sizes, int n_in,
                              void* d_out, int out_size, void* d_ws, size_t ws_size,
                              hipStream_t stream) {
  const float* x  = (const float*)d_in[0];
  const float* y  = (const float*)d_in[1];
  const float* Wq = (const float*)d_in[2];
  const float* Wk = (const float*)d_in[3];
  const float* Wv = (const float*)d_in[4];
  const float* Wp = (const float*)d_in[5];
  const float* bp = (const float*)d_in[6];
  float* out = (float*)d_out;

  const size_t NBH = (size_t)BH * Tt * Dd;  // 3,145,728 elems
  u16t* Qs   = (u16t*)d_ws;
  u16t* Ks   = Qs + NBH;
  u16t* Vts  = Ks + NBH;
  u16t* attb = Vts + NBH;      // [B,T,H*D] internal bf16
  u16t* Wqt  = attb + NBH;     // prepped bf16 weights (transposed)
  u16t* Wkt  = Wqt + 24576;
  u16t* Wvt  = Wkt + 24576;
  u16t* Wpt  = Wvt + 24576;

  prep_kernel<<<96, 256, 0, stream>>>(Wq, Wk, Wv, Wp, Wqt, Wkt, Wvt, Wpt);
  qkv_kernel<<<BH * NQT, 256, 0, stream>>>(x, y, Wqt, Wkt, Wvt, Qs, Ks, Vts);
  attn_kernel<<<BH * NQT, 256, 0, stream>>>(Qs, Ks, Vts, attb);
  proj_kernel<<<(Bb * Tt) / 64, 256, 0, stream>>>(attb, Wpt, bp, out);
}